// Round 2
// baseline (280.928 us; speedup 1.0000x reference)
//
#include <hip/hip_runtime.h>
#include <hip/hip_bf16.h>
#include <math.h>

#define NN 2048
#define NEG_SLOPE 0.2f

typedef __attribute__((ext_vector_type(8))) short short8;
typedef __attribute__((ext_vector_type(4))) float f32x4;

__device__ inline short f2bfs(float f) {
    __hip_bfloat16 h = __float2bfloat16(f);
    return *reinterpret_cast<const short*>(&h);
}
__device__ inline unsigned short f2bfu(float f) {
    __hip_bfloat16 h = __float2bfloat16(f);
    return *reinterpret_cast<const unsigned short*>(&h);
}

// ---------------- GEMM fp32: C[M,N] = A[M,K] @ B[K,N], row-major ----------------
__global__ __launch_bounds__(256) void gemm_fp32(
    const float* __restrict__ A, const float* __restrict__ B, float* __restrict__ C,
    int N, int K)
{
    __shared__ __align__(16) float As[16][68];
    __shared__ __align__(16) float Bs[16][68];
    const int t = threadIdx.x;
    const int tx = t & 15, ty = t >> 4;
    const int i0 = blockIdx.y * 64, c0 = blockIdx.x * 64;
    float acc[4][4] = {};
    for (int k0 = 0; k0 < K; k0 += 16) {
        {
            const int row = t >> 2, kq = (t & 3) << 2;
            const float4 av = *(const float4*)&A[(size_t)(i0 + row) * K + k0 + kq];
            As[kq + 0][row] = av.x; As[kq + 1][row] = av.y;
            As[kq + 2][row] = av.z; As[kq + 3][row] = av.w;
            const int kk = t >> 4, n4 = (t & 15) << 2;
            *(float4*)&Bs[kk][n4] = *(const float4*)&B[(size_t)(k0 + kk) * N + c0 + n4];
        }
        __syncthreads();
        #pragma unroll
        for (int kk = 0; kk < 16; ++kk) {
            const float4 av = *(const float4*)&As[kk][ty << 2];
            const float4 bv = *(const float4*)&Bs[kk][tx << 2];
            const float a_[4] = {av.x, av.y, av.z, av.w};
            const float b_[4] = {bv.x, bv.y, bv.z, bv.w};
            #pragma unroll
            for (int r = 0; r < 4; ++r)
                #pragma unroll
                for (int c = 0; c < 4; ++c)
                    acc[r][c] += a_[r] * b_[c];
        }
        __syncthreads();
    }
    #pragma unroll
    for (int r = 0; r < 4; ++r) {
        const float4 o = make_float4(acc[r][0], acc[r][1], acc[r][2], acc[r][3]);
        *(float4*)&C[(size_t)(i0 + (ty << 2) + r) * N + c0 + (tx << 2)] = o;
    }
}

// ---------------- attention scores ----------------
__global__ __launch_bounds__(256) void score_fp32(
    const float* __restrict__ g, const float* __restrict__ a,
    float* __restrict__ sl, float* __restrict__ sr,
    int gcols, int dh, int nh)
{
    const int wid = (int)((blockIdx.x * blockDim.x + threadIdx.x) >> 6);
    const int lane = threadIdx.x & 63;
    const int i = wid / nh, h = wid - i * nh;
    if (i >= NN) return;
    float vsl = 0.f, vsr = 0.f;
    for (int q = 0; q < dh; q += 64) {
        const float gv = g[(size_t)i * gcols + h * dh + q + lane];
        vsl += gv * a[q + lane];
        vsr += gv * a[dh + q + lane];
    }
    #pragma unroll
    for (int off = 32; off > 0; off >>= 1) {
        vsl += __shfl_down(vsl, off);
        vsr += __shfl_down(vsr, off);
    }
    if (lane == 0) { sl[wid] = vsl; sr[wid] = vsr; }
}

// ---------------- fused masked-softmax attention, MFMA PV ----------------
// out[i, c0+f] = (1/Z_i) * sum_j adj[i,j] * exp(LR(sl[i]+sr[j])) * g[j, c0+f]
// BM=32 rows, FB=64 feats per block; 256 threads = 4 waves.
// wave w: m-tile = w&1 (16 rows), n-half = w>>1 (32 feats, two 16x16 n-tiles).
// A-operand (w weights) computed in registers in MFMA frag order:
//   k = 4*(l>>4) + (t&3) + 16*(t>>2)  [m162-verified layout]
// g staged bf16 in 4 subtiles [64 j][stride 20]; stride 20 => B-frag
//   ds_read_u16 bank = (10k + n/2)%32 covers all 32 banks: conflict-free.
__global__ __launch_bounds__(256) void attn_mfma(
    const float* __restrict__ g, const float* __restrict__ slv, const float* __restrict__ srv,
    const int* __restrict__ adj, float* __restrict__ out,
    int gcols, int out_cols, int nh, int hsel, int do_elu)
{
    const int t = threadIdx.x;
    const int w = t >> 6, l = t & 63;
    const int gq = l >> 4, n16 = l & 15;
    const int m = w & 1, npair = w >> 1;
    const int i0 = blockIdx.x * 32;
    const int h = (hsel < 0) ? (int)blockIdx.y : hsel;
    const int c0 = blockIdx.y * 64;

    __shared__ __align__(16) unsigned short gs[4][64][20];  // 10240 B
    __shared__ unsigned long long adjm[32];
    __shared__ float sr_s[64];
    __shared__ float z_s[32];

    const float sl_reg = slv[(size_t)(i0 + 16 * m + n16) * nh + h];

    f32x4 acc[2] = {f32x4{0.f, 0.f, 0.f, 0.f}, f32x4{0.f, 0.f, 0.f, 0.f}};
    float zacc = 0.f;

    for (int j0 = 0; j0 < NN; j0 += 64) {
        // ---- stage adjacency as per-row 64-bit masks (wave w: rows 8w..8w+7) ----
        #pragma unroll
        for (int r = 0; r < 8; ++r) {
            const int row = w * 8 + r;
            const int v = adj[(size_t)(i0 + row) * NN + j0 + l];
            const unsigned long long bm = __ballot(v != 0);
            if (l == 0) adjm[row] = bm;
        }
        if (t < 64) sr_s[t] = srv[(size_t)(j0 + t) * nh + h];
        // ---- stage g tile as bf16, 4 subtiles of [64][20] ----
        #pragma unroll
        for (int q = 0; q < 4; ++q) {
            const int idx = (q << 8) + t;
            const int jj = idx >> 4, fo = (idx & 15) << 2;
            const float4 gv = *(const float4*)&g[(size_t)(j0 + jj) * gcols + c0 + fo];
            ushort4 u;
            u.x = f2bfu(gv.x); u.y = f2bfu(gv.y); u.z = f2bfu(gv.z); u.w = f2bfu(gv.w);
            *(ushort4*)&gs[fo >> 4][jj][fo & 15] = u;
        }
        __syncthreads();

        const unsigned long long am = adjm[16 * m + n16];
        const unsigned mlo = (unsigned)am, mhi = (unsigned)(am >> 32);

        // ---- A-frag (attention weights) in registers, frag order ----
        short8 afrag[2];
        #pragma unroll
        for (int s = 0; s < 2; ++s) {
            const unsigned mb = s ? mhi : mlo;
            const f32x4 sa = *(const f32x4*)&sr_s[32 * s + 4 * gq];
            const f32x4 sb = *(const f32x4*)&sr_s[32 * s + 16 + 4 * gq];
            #pragma unroll
            for (int c = 0; c < 4; ++c) {
                const int ja = 4 * gq + c;
                float ea = sl_reg + sa[c];
                ea = fmaxf(ea, NEG_SLOPE * ea);
                const float wa = ((mb >> ja) & 1u) ? __expf(ea) : 0.f;
                float eb = sl_reg + sb[c];
                eb = fmaxf(eb, NEG_SLOPE * eb);
                const float wb = ((mb >> (ja + 16)) & 1u) ? __expf(eb) : 0.f;
                zacc += wa + wb;
                afrag[s][c] = f2bfs(wa);
                afrag[s][c + 4] = f2bfs(wb);
            }
        }
        // ---- B-frags from LDS + MFMA ----
        #pragma unroll
        for (int s = 0; s < 2; ++s) {
            #pragma unroll
            for (int nt = 0; nt < 2; ++nt) {
                const int nti = 2 * npair + nt;
                short8 bfrag;
                #pragma unroll
                for (int e = 0; e < 8; ++e) {
                    const int k = 32 * s + 4 * gq + (e & 3) + 16 * (e >> 2);
                    bfrag[e] = (short)gs[nti][k][n16];
                }
                acc[nt] = __builtin_amdgcn_mfma_f32_16x16x32_bf16(afrag[s], bfrag, acc[nt], 0, 0, 0);
            }
        }
        __syncthreads();
    }

    // ---- Z reduction: lanes {l, l^16, l^32, l^48} hold partials for row n16 ----
    zacc += __shfl_xor(zacc, 16);
    zacc += __shfl_xor(zacc, 32);
    if (w < 2 && l < 16) z_s[16 * m + l] = zacc;
    __syncthreads();

    // ---- normalize + optional ELU + store (C/D: col=l&15, row=4*(l>>4)+r) ----
    #pragma unroll
    for (int r = 0; r < 4; ++r) {
        const float rz = 1.0f / z_s[16 * m + 4 * gq + r];
        const int rowi = i0 + 16 * m + 4 * gq + r;
        #pragma unroll
        for (int nt = 0; nt < 2; ++nt) {
            float o = acc[nt][r] * rz;
            if (do_elu) o = (o > 0.f) ? o : (__expf(o) - 1.f);
            out[(size_t)rowi * out_cols + c0 + 32 * npair + 16 * nt + n16] = o;
        }
    }
}

extern "C" void kernel_launch(void* const* d_in, const int* in_sizes, int n_in,
                              void* d_out, int out_size, void* d_ws, size_t ws_size,
                              hipStream_t stream)
{
    const float* x   = (const float*)d_in[0];   // 2048 x 512
    const int*   adj = (const int*)  d_in[1];   // 2048 x 2048
    const float* W1  = (const float*)d_in[2];   // 512 x 512
    const float* a1  = (const float*)d_in[3];   // 128
    const float* W2  = (const float*)d_in[4];   // 512 x 256
    const float* a2  = (const float*)d_in[5];   // 512
    float* out = (float*)d_out;                 // 2048 x 256

    float* g1  = (float*)d_ws;                  // 2048*512
    float* hb  = g1 + 2048 * 512;               // 2048*512
    float* g2  = hb + 2048 * 512;               // 2048*256
    float* sl1 = g2 + 2048 * 256;               // 2048*8
    float* sr1 = sl1 + 2048 * 8;                // 2048*8
    float* sl2 = sr1 + 2048 * 8;                // 2048
    float* sr2 = sl2 + 2048;                    // 2048

    // ---- layer 1 ----
    gemm_fp32<<<dim3(512 / 64, 2048 / 64), 256, 0, stream>>>(x, W1, g1, 512, 512);
    score_fp32<<<dim3((2048 * 8) / 4), 256, 0, stream>>>(g1, a1, sl1, sr1, 512, 64, 8);
    attn_mfma<<<dim3(2048 / 32, 8), 256, 0, stream>>>(g1, sl1, sr1, adj, hb, 512, 512, 8, -1, 1);

    // ---- layer 2 ----
    gemm_fp32<<<dim3(256 / 64, 2048 / 64), 256, 0, stream>>>(hb, W2, g2, 256, 512);
    score_fp32<<<dim3(2048 / 4), 256, 0, stream>>>(g2, a2, sl2, sr2, 256, 256, 1);
    attn_mfma<<<dim3(2048 / 32, 4), 256, 0, stream>>>(g2, sl2, sr2, adj, out, 256, 256, 1, 0, 0);
}

// Round 4
// 152.996 us; speedup vs baseline: 1.8362x; 1.8362x over previous
//
#include <hip/hip_runtime.h>
#include <hip/hip_bf16.h>
#include <math.h>

#define NN 2048
#define LOG2E 1.4426950408889634f

typedef __attribute__((ext_vector_type(8))) short short8;
typedef __attribute__((ext_vector_type(4))) float f32x4;

__device__ inline unsigned short f2bfu(float f) {
    __hip_bfloat16 h = __float2bfloat16(f);
    return *reinterpret_cast<const unsigned short*>(&h);
}
__device__ inline short f2bfs(float f) {
    __hip_bfloat16 h = __float2bfloat16(f);
    return *reinterpret_cast<const short*>(&h);
}

// ---------------- GEMM fp32: C[M,N] = A[M,K] @ B[K,N], row-major ----------------
__global__ __launch_bounds__(256) void gemm_fp32(
    const float* __restrict__ A, const float* __restrict__ B, float* __restrict__ C,
    int N, int K)
{
    __shared__ __align__(16) float As[16][68];
    __shared__ __align__(16) float Bs[16][68];
    const int t = threadIdx.x;
    const int tx = t & 15, ty = t >> 4;
    const int i0 = blockIdx.y * 64, c0 = blockIdx.x * 64;
    float acc[4][4] = {};
    for (int k0 = 0; k0 < K; k0 += 16) {
        {
            const int row = t >> 2, kq = (t & 3) << 2;
            const float4 av = *(const float4*)&A[(size_t)(i0 + row) * K + k0 + kq];
            As[kq + 0][row] = av.x; As[kq + 1][row] = av.y;
            As[kq + 2][row] = av.z; As[kq + 3][row] = av.w;
            const int kk = t >> 4, n4 = (t & 15) << 2;
            *(float4*)&Bs[kk][n4] = *(const float4*)&B[(size_t)(k0 + kk) * N + c0 + n4];
        }
        __syncthreads();
        #pragma unroll
        for (int kk = 0; kk < 16; ++kk) {
            const float4 av = *(const float4*)&As[kk][ty << 2];
            const float4 bv = *(const float4*)&Bs[kk][tx << 2];
            const float a_[4] = {av.x, av.y, av.z, av.w};
            const float b_[4] = {bv.x, bv.y, bv.z, bv.w};
            #pragma unroll
            for (int r = 0; r < 4; ++r)
                #pragma unroll
                for (int c = 0; c < 4; ++c)
                    acc[r][c] += a_[r] * b_[c];
        }
        __syncthreads();
    }
    #pragma unroll
    for (int r = 0; r < 4; ++r) {
        const float4 o = make_float4(acc[r][0], acc[r][1], acc[r][2], acc[r][3]);
        *(float4*)&C[(size_t)(i0 + (ty << 2) + r) * N + c0 + (tx << 2)] = o;
    }
}

// ---------------- attention scores (HEAD-MAJOR out, pre-scaled by log2e) --------
// sl[h*NN + i], sr[h*NN + i]  -> attention kernel reads contiguous per head.
__global__ __launch_bounds__(256) void score_fp32(
    const float* __restrict__ g, const float* __restrict__ a,
    float* __restrict__ sl, float* __restrict__ sr,
    int gcols, int dh, int nh)
{
    const int wid = (int)((blockIdx.x * blockDim.x + threadIdx.x) >> 6);
    const int lane = threadIdx.x & 63;
    const int i = wid / nh, h = wid - i * nh;
    if (i >= NN) return;
    float vsl = 0.f, vsr = 0.f;
    for (int q = 0; q < dh; q += 64) {
        const float gv = g[(size_t)i * gcols + h * dh + q + lane];
        vsl += gv * a[q + lane];
        vsr += gv * a[dh + q + lane];
    }
    #pragma unroll
    for (int off = 32; off > 0; off >>= 1) {
        vsl += __shfl_down(vsl, off);
        vsr += __shfl_down(vsr, off);
    }
    if (lane == 0) {
        sl[(size_t)h * NN + i] = vsl * LOG2E;
        sr[(size_t)h * NN + i] = vsr * LOG2E;
    }
}

// ---------------- adjacency -> per-row 64-bit masks ----------------
// adjm[row*32 + ch] has bit b = (adj[row][ch*64+b] != 0)
__global__ __launch_bounds__(256) void pack_adj(
    const int* __restrict__ adj, unsigned long long* __restrict__ adjm)
{
    const int t = threadIdx.x, w = t >> 6, l = t & 63;
    const int gw = blockIdx.x * 4 + w;              // chunk id, 0..65535
    const int row = gw >> 5, ch = gw & 31;
    const int v = adj[(size_t)row * NN + ch * 64 + l];
    const unsigned long long bm = __ballot(v != 0);
    if (l == 0) adjm[gw] = bm;
}

// ---------------- g (fp32 row-major) -> bf16 MFMA-B-fragment-packed ----------------
// frag f = jt*NT + ntg covers rows 32*jt..+31, cols 16*ntg..+15.
// lane l, elem e holds g[32*jt + 4*(l>>4) + (e&3) + 16*(e>>2)][16*ntg + (l&15)]
__global__ __launch_bounds__(256) void pack_g(
    const float* __restrict__ g, unsigned short* __restrict__ gp, int gcols)
{
    const int t = threadIdx.x, w = t >> 6, l = t & 63;
    const int gq = l >> 4, n16 = l & 15;
    const int NT = gcols >> 4;
    const int f = blockIdx.x * 4 + w;
    const int jt = f / NT, ntg = f - jt * NT;
    const int j0 = jt * 32, c = ntg * 16 + n16;
    unsigned short u[8];
    #pragma unroll
    for (int e = 0; e < 8; ++e) {
        const int row = j0 + 4 * gq + (e & 3) + 16 * (e >> 2);
        u[e] = f2bfu(g[(size_t)row * gcols + c]);
    }
    *(short8*)&gp[(size_t)f * 512 + l * 8] = *(const short8*)u;
}

// ---------------- fused masked-softmax attention, register-resident MFMA ----------
// out[i, 64*cb + f] = (1/Z_i) * sum_j adj[i,j] * exp(LR(sl_i+sr_j)) * g[j, 64*cb+f]
// 8 waves; wave (wr = w%WR, js = w/WR): rows 16*wr..+15, j-tiles tt = js, js+NJS, ...
// A-frags (w weights) computed in registers; B-frags direct from packed global;
// NO LDS / NO barrier in the main loop. End: cross-js acc + Z reduction via LDS.
// slv/srv are HEAD-MAJOR: s[h*NN + node].
template<int BM>
__global__ __launch_bounds__(512, 2) void attn_mfma3(
    const float* __restrict__ slv, const float* __restrict__ srv,
    const unsigned short* __restrict__ gp, const unsigned long long* __restrict__ adjm,
    float* __restrict__ out, int out_cols, int hsel, int do_elu, int ntg_total)
{
    constexpr int WR = BM / 16;      // m-subtiles (waves over rows)
    constexpr int NJS = 8 / WR;      // j-splits
    constexpr int NTPW = 4 / NJS;    // n-tiles per wave in epilogue
    const int t = threadIdx.x, w = t >> 6, l = t & 63;
    const int gq = l >> 4, n16 = l & 15;
    const int wr = w % WR, js = w / WR;
    const int i0 = blockIdx.x * BM;
    const int cb = blockIdx.y;
    const int h = (hsel < 0) ? cb : hsel;
    const int ntg0 = cb * 4;
    const int arow = i0 + 16 * wr + n16;
    const float* srh = srv + (size_t)h * NN;
    const float sl_reg = slv[(size_t)h * NN + arow];
    const int NT64 = NN / 64;

    __shared__ float accs[NJS][WR][4][4][64];
    __shared__ float zp[NJS][BM];

    f32x4 acc[4];
    #pragma unroll
    for (int nt = 0; nt < 4; ++nt) acc[nt] = f32x4{0.f, 0.f, 0.f, 0.f};
    float zacc = 0.f;

    // ---- prefetch tile tt=js ----
    int tt = js;
    unsigned long long am_n = adjm[(size_t)arow * 32 + tt];
    f32x4 sr_n[4];
    #pragma unroll
    for (int q = 0; q < 4; ++q)
        sr_n[q] = *(const f32x4*)&srh[64 * tt + 32 * (q >> 1) + 16 * (q & 1) + 4 * gq];
    short8 bf_n[2][4];
    #pragma unroll
    for (int s = 0; s < 2; ++s)
        #pragma unroll
        for (int nt = 0; nt < 4; ++nt)
            bf_n[s][nt] = *(const short8*)&gp[(size_t)((2 * tt + s) * ntg_total + ntg0 + nt) * 512 + l * 8];

    for (; tt < NT64; tt += NJS) {
        const unsigned long long am = am_n;
        f32x4 sr4[4];
        short8 bfr[2][4];
        #pragma unroll
        for (int q = 0; q < 4; ++q) sr4[q] = sr_n[q];
        #pragma unroll
        for (int s = 0; s < 2; ++s)
            #pragma unroll
            for (int nt = 0; nt < 4; ++nt) bfr[s][nt] = bf_n[s][nt];

        // ---- issue next tile's loads (hidden under this tile's VALU) ----
        int tn = tt + NJS; if (tn >= NT64) tn = tt;
        am_n = adjm[(size_t)arow * 32 + tn];
        #pragma unroll
        for (int q = 0; q < 4; ++q)
            sr_n[q] = *(const f32x4*)&srh[64 * tn + 32 * (q >> 1) + 16 * (q & 1) + 4 * gq];
        #pragma unroll
        for (int s = 0; s < 2; ++s)
            #pragma unroll
            for (int nt = 0; nt < 4; ++nt)
                bf_n[s][nt] = *(const short8*)&gp[(size_t)((2 * tn + s) * ntg_total + ntg0 + nt) * 512 + l * 8];

        // ---- w-gen in A-frag order: elem e=4*hb+c <-> j = 64*tt+32*s+16*hb+4*gq+c ----
        short8 afrag[2];
        #pragma unroll
        for (int s = 0; s < 2; ++s) {
            const unsigned am32 = (unsigned)(am >> (32 * s + 4 * gq));
            #pragma unroll
            for (int hb = 0; hb < 2; ++hb) {
                const f32x4 s4 = sr4[2 * s + hb];
                #pragma unroll
                for (int c = 0; c < 4; ++c) {
                    float f = sl_reg + s4[c];
                    f = fmaxf(f, 0.2f * f);                    // LR in log2e-scaled space
                    float wv = __builtin_amdgcn_exp2f(f);
                    const int pos = c + 16 * hb;
                    const int msk = (int)(am32 << (31 - pos)) >> 31;   // 0 or -1
                    wv = __int_as_float(__float_as_int(wv) & msk);
                    zacc += wv;
                    afrag[s][4 * hb + c] = f2bfs(wv);
                }
            }
        }
        #pragma unroll
        for (int s = 0; s < 2; ++s)
            #pragma unroll
            for (int nt = 0; nt < 4; ++nt)
                acc[nt] = __builtin_amdgcn_mfma_f32_16x16x32_bf16(afrag[s], bfr[s][nt], acc[nt], 0, 0, 0);
    }

    // ---- Z: reduce over gq within wave (lanes l, l^16, l^32, l^48 share a row) ----
    zacc += __shfl_xor(zacc, 16);
    zacc += __shfl_xor(zacc, 32);
    if (l < 16) zp[js][16 * wr + l] = zacc;
    #pragma unroll
    for (int nt = 0; nt < 4; ++nt)
        #pragma unroll
        for (int r = 0; r < 4; ++r)
            accs[js][wr][nt][r][l] = acc[nt][r];
    __syncthreads();

    // ---- cross-js reduce + normalize + (ELU) + store; wave handles NTPW n-tiles ----
    #pragma unroll
    for (int r = 0; r < 4; ++r) {
        const int ro = 16 * wr + 4 * gq + r;
        float z = 0.f;
        #pragma unroll
        for (int jj = 0; jj < NJS; ++jj) z += zp[jj][ro];
        const float rz = 1.0f / z;
        #pragma unroll
        for (int q = 0; q < NTPW; ++q) {
            const int nt = js * NTPW + q;
            float v = 0.f;
            #pragma unroll
            for (int jj = 0; jj < NJS; ++jj) v += accs[jj][wr][nt][r][l];
            float o = v * rz;
            if (do_elu) o = (o > 0.f) ? o : (__builtin_amdgcn_exp2f(o * LOG2E) - 1.f);
            out[(size_t)(i0 + ro) * out_cols + cb * 64 + nt * 16 + n16] = o;
        }
    }
}

extern "C" void kernel_launch(void* const* d_in, const int* in_sizes, int n_in,
                              void* d_out, int out_size, void* d_ws, size_t ws_size,
                              hipStream_t stream)
{
    const float* x   = (const float*)d_in[0];   // 2048 x 512
    const int*   adj = (const int*)  d_in[1];   // 2048 x 2048
    const float* W1  = (const float*)d_in[2];   // 512 x 512
    const float* a1  = (const float*)d_in[3];   // 128
    const float* W2  = (const float*)d_in[4];   // 512 x 256
    const float* a2  = (const float*)d_in[5];   // 512
    float* out = (float*)d_out;                 // 2048 x 256

    float* g1  = (float*)d_ws;                  // 2048*512 fp32
    float* hb  = g1;                            // ALIAS: g1 dead once attn1 runs
    float* g2  = g1 + 2048 * 512;               // 2048*256 fp32
    float* sl1 = g2 + 2048 * 256;               // 8*2048 (head-major)
    float* sr1 = sl1 + 2048 * 8;                // 8*2048
    float* sl2 = sr1 + 2048 * 8;                // 2048
    float* sr2 = sl2 + 2048;                    // 2048
    unsigned long long* adjm = (unsigned long long*)(sr2 + 2048);   // 2048*32 u64
    unsigned short* gp = (unsigned short*)(adjm + 2048 * 32);       // <= 2048 frags * 512

    pack_adj<<<dim3(16384), 256, 0, stream>>>(adj, adjm);

    // ---- layer 1 ----
    gemm_fp32<<<dim3(8, 32), 256, 0, stream>>>(x, W1, g1, 512, 512);
    score_fp32<<<dim3(4096), 256, 0, stream>>>(g1, a1, sl1, sr1, 512, 64, 8);
    pack_g<<<dim3(512), 256, 0, stream>>>(g1, gp, 512);
    attn_mfma3<64><<<dim3(32, 8), 512, 0, stream>>>(sl1, sr1, gp, adjm, hb, 512, -1, 1, 32);

    // ---- layer 2 ----
    gemm_fp32<<<dim3(4, 32), 256, 0, stream>>>(hb, W2, g2, 256, 512);
    score_fp32<<<dim3(512), 256, 0, stream>>>(g2, a2, sl2, sr2, 256, 256, 1);
    pack_g<<<dim3(256), 256, 0, stream>>>(g2, gp, 256);
    attn_mfma3<32><<<dim3(64, 4), 512, 0, stream>>>(sl2, sr2, gp, adjm, out, 256, 0, 0, 16);
}

// Round 5
// 113.764 us; speedup vs baseline: 2.4694x; 1.3449x over previous
//
#include <hip/hip_runtime.h>
#include <hip/hip_bf16.h>
#include <math.h>

#define NN 2048
#define LOG2E 1.4426950408889634f

typedef __attribute__((ext_vector_type(8))) short short8;
typedef __attribute__((ext_vector_type(4))) float f32x4;

__device__ inline unsigned short f2bfu(float f) {
    __hip_bfloat16 h = __float2bfloat16(f);
    return *reinterpret_cast<const unsigned short*>(&h);
}
__device__ inline short f2bfs(float f) {
    __hip_bfloat16 h = __float2bfloat16(f);
    return *reinterpret_cast<const short*>(&h);
}

// ---------------- GEMM fp32: C[M,N] = A[M,K] @ B[K,N], row-major ----------------
__global__ __launch_bounds__(256) void gemm_fp32(
    const float* __restrict__ A, const float* __restrict__ B, float* __restrict__ C,
    int N, int K)
{
    __shared__ __align__(16) float As[16][68];
    __shared__ __align__(16) float Bs[16][68];
    const int t = threadIdx.x;
    const int tx = t & 15, ty = t >> 4;
    const int i0 = blockIdx.y * 64, c0 = blockIdx.x * 64;
    float acc[4][4] = {};
    for (int k0 = 0; k0 < K; k0 += 16) {
        {
            const int row = t >> 2, kq = (t & 3) << 2;
            const float4 av = *(const float4*)&A[(size_t)(i0 + row) * K + k0 + kq];
            As[kq + 0][row] = av.x; As[kq + 1][row] = av.y;
            As[kq + 2][row] = av.z; As[kq + 3][row] = av.w;
            const int kk = t >> 4, n4 = (t & 15) << 2;
            *(float4*)&Bs[kk][n4] = *(const float4*)&B[(size_t)(k0 + kk) * N + c0 + n4];
        }
        __syncthreads();
        #pragma unroll
        for (int kk = 0; kk < 16; ++kk) {
            const float4 av = *(const float4*)&As[kk][ty << 2];
            const float4 bv = *(const float4*)&Bs[kk][tx << 2];
            const float a_[4] = {av.x, av.y, av.z, av.w};
            const float b_[4] = {bv.x, bv.y, bv.z, bv.w};
            #pragma unroll
            for (int r = 0; r < 4; ++r)
                #pragma unroll
                for (int c = 0; c < 4; ++c)
                    acc[r][c] += a_[r] * b_[c];
        }
        __syncthreads();
    }
    #pragma unroll
    for (int r = 0; r < 4; ++r) {
        const float4 o = make_float4(acc[r][0], acc[r][1], acc[r][2], acc[r][3]);
        *(float4*)&C[(size_t)(i0 + (ty << 2) + r) * N + c0 + (tx << 2)] = o;
    }
}

// ---------------- attention scores (HEAD-MAJOR out, pre-scaled by log2e) --------
__global__ __launch_bounds__(256) void score_fp32(
    const float* __restrict__ g, const float* __restrict__ a,
    float* __restrict__ sl, float* __restrict__ sr,
    int gcols, int dh, int nh)
{
    const int wid = (int)((blockIdx.x * blockDim.x + threadIdx.x) >> 6);
    const int lane = threadIdx.x & 63;
    const int i = wid / nh, h = wid - i * nh;
    if (i >= NN) return;
    float vsl = 0.f, vsr = 0.f;
    for (int q = 0; q < dh; q += 64) {
        const float gv = g[(size_t)i * gcols + h * dh + q + lane];
        vsl += gv * a[q + lane];
        vsr += gv * a[dh + q + lane];
    }
    #pragma unroll
    for (int off = 32; off > 0; off >>= 1) {
        vsl += __shfl_down(vsl, off);
        vsr += __shfl_down(vsr, off);
    }
    if (lane == 0) {
        sl[(size_t)h * NN + i] = vsl * LOG2E;
        sr[(size_t)h * NN + i] = vsr * LOG2E;
    }
}

// ---------------- adjacency -> per-row 64-bit masks ----------------
__global__ __launch_bounds__(256) void pack_adj(
    const int* __restrict__ adj, unsigned long long* __restrict__ adjm)
{
    const int t = threadIdx.x, w = t >> 6, l = t & 63;
    const int gw = blockIdx.x * 4 + w;
    const int row = gw >> 5, ch = gw & 31;
    const int v = adj[(size_t)row * NN + ch * 64 + l];
    const unsigned long long bm = __ballot(v != 0);
    if (l == 0) adjm[gw] = bm;
}

// ---------------- g (fp32 row-major) -> bf16 MFMA-B-fragment-packed ----------------
__global__ __launch_bounds__(256) void pack_g(
    const float* __restrict__ g, unsigned short* __restrict__ gp, int gcols)
{
    const int t = threadIdx.x, w = t >> 6, l = t & 63;
    const int gq = l >> 4, n16 = l & 15;
    const int NT = gcols >> 4;
    const int f = blockIdx.x * 4 + w;
    const int jt = f / NT, ntg = f - jt * NT;
    const int j0 = jt * 32, c = ntg * 16 + n16;
    unsigned short u[8];
    #pragma unroll
    for (int e = 0; e < 8; ++e) {
        const int row = j0 + 4 * gq + (e & 3) + 16 * (e >> 2);
        u[e] = f2bfu(g[(size_t)row * gcols + c]);
    }
    *(short8*)&gp[(size_t)f * 512 + l * 8] = *(const short8*)u;
}

// ---------------- fused masked-softmax attention, register ping-pong MFMA ---------
// 8 waves: wave w = (wr = w%WR rows-subtile, js = w/WR j-split).
// Two named register buffers (A/B); compute(bufX) then reload bufX for tile k+2:
// no reg copies -> compiler emits counted vmcnt (other buffer's 9 loads in flight).
template<int BM>
__global__ __launch_bounds__(512, 4) void attn_mfma4(
    const float* __restrict__ slv, const float* __restrict__ srv,
    const unsigned short* __restrict__ gp, const unsigned long long* __restrict__ adjm,
    float* __restrict__ out, int out_cols, int hsel, int do_elu, int ntg_total)
{
    constexpr int WR = BM / 16;              // waves over rows
    constexpr int NJS = 8 / WR;              // j-splits
    constexpr int NITER = (NN / 64) / NJS;   // 8 (BM=32) / 4 (BM=16) -- even
    const int t = threadIdx.x, w = t >> 6, l = t & 63;
    const int gq = l >> 4, n16 = l & 15;
    const int wr = w % WR, js = w / WR;
    const int i0 = blockIdx.x * BM;
    const int cb = blockIdx.y;
    const int h = (hsel < 0) ? cb : hsel;
    const int ntg0 = cb * 4;
    const int arow = i0 + 16 * wr + n16;
    const float* srh = srv + (size_t)h * NN;
    const float sl_reg = slv[(size_t)h * NN + arow];

    __shared__ float accs[8][4][4][64];      // [w][nt][r][lane]
    __shared__ float zp[NJS][BM];

    f32x4 acc[4];
    #pragma unroll
    for (int nt = 0; nt < 4; ++nt) acc[nt] = f32x4{0.f, 0.f, 0.f, 0.f};
    float zacc = 0.f;

#define LOADT(am_, bf_, tile_) do {                                              \
    const int tl_ = (tile_);                                                     \
    am_ = adjm[(size_t)arow * 32 + tl_];                                         \
    _Pragma("unroll")                                                            \
    for (int s_ = 0; s_ < 2; ++s_)                                               \
        _Pragma("unroll")                                                        \
        for (int nt_ = 0; nt_ < 4; ++nt_)                                        \
            bf_[s_][nt_] = *(const short8*)&gp[                                  \
                (size_t)((2 * tl_ + s_) * ntg_total + ntg0 + nt_) * 512 + l * 8];\
} while (0)

#define COMPT(am_, bf_, tile_) do {                                              \
    const int tl_ = (tile_);                                                     \
    f32x4 sr4_[4];                                                               \
    _Pragma("unroll")                                                            \
    for (int q_ = 0; q_ < 4; ++q_)                                               \
        sr4_[q_] = *(const f32x4*)&srh[64 * tl_ + 32 * (q_ >> 1) + 16 * (q_ & 1) + 4 * gq]; \
    short8 af_[2];                                                               \
    _Pragma("unroll")                                                            \
    for (int s_ = 0; s_ < 2; ++s_) {                                             \
        const unsigned am32_ = (unsigned)(am_ >> (32 * s_ + 4 * gq));            \
        _Pragma("unroll")                                                        \
        for (int hb_ = 0; hb_ < 2; ++hb_) {                                      \
            const f32x4 s4_ = sr4_[2 * s_ + hb_];                                \
            _Pragma("unroll")                                                    \
            for (int c_ = 0; c_ < 4; ++c_) {                                     \
                float f_ = sl_reg + s4_[c_];                                     \
                f_ = fmaxf(f_, 0.2f * f_);                                       \
                float wv_ = __builtin_amdgcn_exp2f(f_);                          \
                const int msk_ = (int)(am32_ << (31 - (c_ + 16 * hb_))) >> 31;   \
                wv_ = __int_as_float(__float_as_int(wv_) & msk_);                \
                zacc += wv_;                                                     \
                af_[s_][4 * hb_ + c_] = f2bfs(wv_);                              \
            }                                                                    \
        }                                                                        \
    }                                                                            \
    _Pragma("unroll")                                                            \
    for (int s_ = 0; s_ < 2; ++s_)                                               \
        _Pragma("unroll")                                                        \
        for (int nt_ = 0; nt_ < 4; ++nt_)                                        \
            acc[nt_] = __builtin_amdgcn_mfma_f32_16x16x32_bf16(                  \
                af_[s_], bf_[s_][nt_], acc[nt_], 0, 0, 0);                       \
} while (0)

    unsigned long long amA, amB;
    short8 bfA[2][4], bfB[2][4];

    LOADT(amA, bfA, js);
    LOADT(amB, bfB, js + NJS);

    for (int k = 0; k < NITER; k += 2) {
        COMPT(amA, bfA, js + k * NJS);
        {
            const int kn = (k + 2 < NITER) ? (k + 2) : (NITER - 1);
            LOADT(amA, bfA, js + kn * NJS);
        }
        COMPT(amB, bfB, js + (k + 1) * NJS);
        {
            const int kn = (k + 3 < NITER) ? (k + 3) : (NITER - 1);
            LOADT(amB, bfB, js + kn * NJS);
        }
    }
#undef LOADT
#undef COMPT

    // ---- Z: lanes {l, l^16, l^32, l^48} hold partials of the same row ----
    zacc += __shfl_xor(zacc, 16);
    zacc += __shfl_xor(zacc, 32);
    if (l < 16) zp[js][16 * wr + l] = zacc;
    #pragma unroll
    for (int nt = 0; nt < 4; ++nt)
        #pragma unroll
        for (int r = 0; r < 4; ++r)
            accs[w][nt][r][l] = acc[nt][r];
    __syncthreads();

    // ---- cross-js reduce + normalize + (ELU) + store; flat triple assignment ----
    #pragma unroll
    for (int idx = 0; idx < WR * 2; ++idx) {
        const int flat = w + 8 * idx;            // 0 .. WR*16-1, bijective
        const int wr2 = flat >> 4, rem = flat & 15, nt = rem >> 2, r = rem & 3;
        const int ro = 16 * wr2 + 4 * gq + r;
        float z = 0.f, v = 0.f;
        #pragma unroll
        for (int jj = 0; jj < NJS; ++jj) {
            z += zp[jj][ro];
            v += accs[jj * WR + wr2][nt][r][l];
        }
        float o = v / z;
        if (do_elu) o = (o > 0.f) ? o : (__builtin_amdgcn_exp2f(o * LOG2E) - 1.f);
        out[(size_t)(i0 + ro) * out_cols + cb * 64 + nt * 16 + n16] = o;
    }
}

extern "C" void kernel_launch(void* const* d_in, const int* in_sizes, int n_in,
                              void* d_out, int out_size, void* d_ws, size_t ws_size,
                              hipStream_t stream)
{
    const float* x   = (const float*)d_in[0];   // 2048 x 512
    const int*   adj = (const int*)  d_in[1];   // 2048 x 2048
    const float* W1  = (const float*)d_in[2];   // 512 x 512
    const float* a1  = (const float*)d_in[3];   // 128
    const float* W2  = (const float*)d_in[4];   // 512 x 256
    const float* a2  = (const float*)d_in[5];   // 512
    float* out = (float*)d_out;                 // 2048 x 256

    float* g1  = (float*)d_ws;                  // 2048*512 fp32
    float* hb  = g1;                            // ALIAS: g1 dead once attn1 runs
    float* g2  = g1 + 2048 * 512;               // 2048*256 fp32
    float* sl1 = g2 + 2048 * 256;               // 8*2048 (head-major)
    float* sr1 = sl1 + 2048 * 8;                // 8*2048
    float* sl2 = sr1 + 2048 * 8;                // 2048
    float* sr2 = sl2 + 2048;                    // 2048
    unsigned long long* adjm = (unsigned long long*)(sr2 + 2048);   // 2048*32 u64
    unsigned short* gp = (unsigned short*)(adjm + 2048 * 32);       // <= 2048 frags * 512

    pack_adj<<<dim3(16384), 256, 0, stream>>>(adj, adjm);

    // ---- layer 1 ----
    gemm_fp32<<<dim3(8, 32), 256, 0, stream>>>(x, W1, g1, 512, 512);
    score_fp32<<<dim3(4096), 256, 0, stream>>>(g1, a1, sl1, sr1, 512, 64, 8);
    pack_g<<<dim3(512), 256, 0, stream>>>(g1, gp, 512);
    attn_mfma4<32><<<dim3(64, 8), 512, 0, stream>>>(sl1, sr1, gp, adjm, hb, 512, -1, 1, 32);

    // ---- layer 2 ----
    gemm_fp32<<<dim3(4, 32), 256, 0, stream>>>(hb, W2, g2, 256, 512);
    score_fp32<<<dim3(512), 256, 0, stream>>>(g2, a2, sl2, sr2, 256, 256, 1);
    pack_g<<<dim3(256), 256, 0, stream>>>(g2, gp, 256);
    attn_mfma4<16><<<dim3(128, 4), 512, 0, stream>>>(sl2, sr2, gp, adjm, out, 256, 0, 0, 16);
}

// Round 6
// 81.442 us; speedup vs baseline: 3.4494x; 1.3969x over previous
//
#include <hip/hip_runtime.h>
#include <hip/hip_bf16.h>
#include <math.h>

#define NN 2048
#define LOG2E 1.4426950408889634f

typedef __attribute__((ext_vector_type(8))) short short8;
typedef __attribute__((ext_vector_type(4))) float f32x4;

__device__ inline unsigned short f2bfu(float f) {
    __hip_bfloat16 h = __float2bfloat16(f);
    return *reinterpret_cast<const unsigned short*>(&h);
}
__device__ inline short f2bfs(float f) {
    __hip_bfloat16 h = __float2bfloat16(f);
    return *reinterpret_cast<const short*>(&h);
}
__device__ inline float bfu2f(unsigned short u) {
    return __uint_as_float(((unsigned int)u) << 16);
}

// ---------------- attention scores (HEAD-MAJOR out, pre-scaled by log2e) --------
__global__ __launch_bounds__(256) void score_fp32(
    const float* __restrict__ g, const float* __restrict__ a,
    float* __restrict__ sl, float* __restrict__ sr,
    int gcols, int dh, int nh)
{
    const int wid = (int)((blockIdx.x * blockDim.x + threadIdx.x) >> 6);
    const int lane = threadIdx.x & 63;
    const int i = wid / nh, h = wid - i * nh;
    if (i >= NN) return;
    float vsl = 0.f, vsr = 0.f;
    for (int q = 0; q < dh; q += 64) {
        const float gv = g[(size_t)i * gcols + h * dh + q + lane];
        vsl += gv * a[q + lane];
        vsr += gv * a[dh + q + lane];
    }
    #pragma unroll
    for (int off = 32; off > 0; off >>= 1) {
        vsl += __shfl_down(vsl, off);
        vsr += __shfl_down(vsr, off);
    }
    if (lane == 0) {
        sl[(size_t)h * NN + i] = vsl * LOG2E;
        sr[(size_t)h * NN + i] = vsr * LOG2E;
    }
}

// ---------------- adjacency -> per-row 64-bit masks ----------------
__global__ __launch_bounds__(256) void pack_adj(
    const int* __restrict__ adj, unsigned long long* __restrict__ adjm)
{
    const int t = threadIdx.x, w = t >> 6, l = t & 63;
    const int gw = blockIdx.x * 4 + w;
    const int row = gw >> 5, ch = gw & 31;
    const int v = adj[(size_t)row * NN + ch * 64 + l];
    const unsigned long long bm = __ballot(v != 0);
    if (l == 0) adjm[gw] = bm;
}

// ---------------- g (fp32 row-major) -> bf16 MFMA-B-frag (attention PV) ----------
// frag f = jt*NT + ntg; lane l elem e: g[32*jt + 4*(l>>4)+(e&3)+16*(e>>2)][16*ntg+(l&15)]
__global__ __launch_bounds__(256) void pack_g(
    const float* __restrict__ g, unsigned short* __restrict__ gp, int gcols)
{
    const int t = threadIdx.x, w = t >> 6, l = t & 63;
    const int gq = l >> 4, n16 = l & 15;
    const int NT = gcols >> 4;
    const int f = blockIdx.x * 4 + w;
    const int jt = f / NT, ntg = f - jt * NT;
    const int j0 = jt * 32, c = ntg * 16 + n16;
    unsigned short u[8];
    #pragma unroll
    for (int e = 0; e < 8; ++e) {
        const int row = j0 + 4 * gq + (e & 3) + 16 * (e >> 2);
        u[e] = f2bfu(g[(size_t)row * gcols + c]);
    }
    *(short8*)&gp[(size_t)f * 512 + l * 8] = *(const short8*)u;
}

// ---------------- A (M x K fp32) -> split-bf16 A-frags -----------------------------
// frag f = mt*KT + kt; lane l elem e: A[mt*16 + (l&15)][kt*32 + 4*(l>>4)+(e&3)+16*(e>>2)]
__global__ __launch_bounds__(256) void pack_a_split(
    const float* __restrict__ A, unsigned short* __restrict__ aH,
    unsigned short* __restrict__ aL, int K)
{
    const int t = threadIdx.x, w = t >> 6, l = t & 63;
    const int gq = l >> 4, n16 = l & 15;
    const int KT = K >> 5;
    const int f = blockIdx.x * 4 + w;
    const int mt = f / KT, kt = f - mt * KT;
    const int row = mt * 16 + n16;
    const int k0 = kt * 32 + 4 * gq;
    unsigned short uh[8], ul[8];
    #pragma unroll
    for (int eh = 0; eh < 2; ++eh) {
        const float4 v4 = *(const float4*)&A[(size_t)row * K + k0 + 16 * eh];
        const float vv[4] = {v4.x, v4.y, v4.z, v4.w};
        #pragma unroll
        for (int c = 0; c < 4; ++c) {
            const float v = vv[c];
            const unsigned short h = f2bfu(v);
            uh[4 * eh + c] = h;
            ul[4 * eh + c] = f2bfu(v - bfu2f(h));
        }
    }
    *(short8*)&aH[(size_t)f * 512 + l * 8] = *(const short8*)uh;
    *(short8*)&aL[(size_t)f * 512 + l * 8] = *(const short8*)ul;
}

// ---------------- B (K x N fp32) -> split-bf16 B-frags -----------------------------
// frag f = nt*KT + kt; lane l elem e: B[kt*32 + 4*(l>>4)+(e&3)+16*(e>>2)][nt*16 + (l&15)]
__global__ __launch_bounds__(256) void pack_b_split(
    const float* __restrict__ B, unsigned short* __restrict__ bH,
    unsigned short* __restrict__ bL, int N, int KT)
{
    const int t = threadIdx.x, w = t >> 6, l = t & 63;
    const int gq = l >> 4, n16 = l & 15;
    const int f = blockIdx.x * 4 + w;
    const int nt = f / KT, kt = f - nt * KT;
    const int col = nt * 16 + n16;
    unsigned short uh[8], ul[8];
    #pragma unroll
    for (int e = 0; e < 8; ++e) {
        const int k = kt * 32 + 4 * gq + (e & 3) + 16 * (e >> 2);
        const float v = B[(size_t)k * N + col];
        const unsigned short h = f2bfu(v);
        uh[e] = h;
        ul[e] = f2bfu(v - bfu2f(h));
    }
    *(short8*)&bH[(size_t)f * 512 + l * 8] = *(const short8*)uh;
    *(short8*)&bL[(size_t)f * 512 + l * 8] = *(const short8*)ul;
}

// ---------------- split-bf16 MFMA GEMM: C = A@B (fp32-accurate) --------------------
// AB ~= AhBh + AhBl + AlBh. Register ping-pong, no LDS, no barriers.
// 4 waves/block; wave = 16 rows x 64 cols; grid (M/64, N/64).
__global__ __launch_bounds__(256, 2) void gemm_mfma_split(
    const unsigned short* __restrict__ aH, const unsigned short* __restrict__ aL,
    const unsigned short* __restrict__ bH, const unsigned short* __restrict__ bL,
    float* __restrict__ C, int N, int KT)
{
    const int t = threadIdx.x, w = t >> 6, l = t & 63;
    const int gq = l >> 4, n16 = l & 15;
    const int mt = blockIdx.x * 4 + w;
    const int nt0 = blockIdx.y * 4;
    const size_t abase = (size_t)mt * KT * 512 + l * 8;

    f32x4 acc[4];
    #pragma unroll
    for (int nt = 0; nt < 4; ++nt) acc[nt] = f32x4{0.f, 0.f, 0.f, 0.f};

#define GL(aH_v, aL_v, bH_v, bL_v, kt_) do {                                     \
    const int kk_ = (kt_);                                                       \
    aH_v = *(const short8*)&aH[abase + (size_t)kk_ * 512];                       \
    aL_v = *(const short8*)&aL[abase + (size_t)kk_ * 512];                       \
    _Pragma("unroll")                                                            \
    for (int nt_ = 0; nt_ < 4; ++nt_) {                                          \
        const size_t bo_ = ((size_t)(nt0 + nt_) * KT + kk_) * 512 + l * 8;       \
        bH_v[nt_] = *(const short8*)&bH[bo_];                                    \
        bL_v[nt_] = *(const short8*)&bL[bo_];                                    \
    }                                                                            \
} while (0)

#define GC(aH_v, aL_v, bH_v, bL_v) do {                                          \
    _Pragma("unroll")                                                            \
    for (int nt_ = 0; nt_ < 4; ++nt_) {                                          \
        acc[nt_] = __builtin_amdgcn_mfma_f32_16x16x32_bf16(aH_v, bH_v[nt_], acc[nt_], 0, 0, 0); \
        acc[nt_] = __builtin_amdgcn_mfma_f32_16x16x32_bf16(aH_v, bL_v[nt_], acc[nt_], 0, 0, 0); \
        acc[nt_] = __builtin_amdgcn_mfma_f32_16x16x32_bf16(aL_v, bH_v[nt_], acc[nt_], 0, 0, 0); \
    }                                                                            \
} while (0)

    short8 aHa, aLa, bHa[4], bLa[4], aHb, aLb, bHb[4], bLb[4];
    GL(aHa, aLa, bHa, bLa, 0);
    GL(aHb, aLb, bHb, bLb, 1);
    for (int kt = 0; kt < KT; kt += 2) {
        GC(aHa, aLa, bHa, bLa);
        if (kt + 2 < KT) GL(aHa, aLa, bHa, bLa, kt + 2);
        GC(aHb, aLb, bHb, bLb);
        if (kt + 3 < KT) GL(aHb, aLb, bHb, bLb, kt + 3);
    }
#undef GL
#undef GC

    #pragma unroll
    for (int nt = 0; nt < 4; ++nt)
        #pragma unroll
        for (int r = 0; r < 4; ++r)
            C[(size_t)(mt * 16 + 4 * gq + r) * N + (nt0 + nt) * 16 + n16] = acc[nt][r];
}

// ---------------- fused masked-softmax attention, register ping-pong MFMA ---------
template<int BM>
__global__ __launch_bounds__(512, 4) void attn_mfma4(
    const float* __restrict__ slv, const float* __restrict__ srv,
    const unsigned short* __restrict__ gp, const unsigned long long* __restrict__ adjm,
    float* __restrict__ out, int out_cols, int hsel, int do_elu, int ntg_total)
{
    constexpr int WR = BM / 16;
    constexpr int NJS = 8 / WR;
    constexpr int NITER = (NN / 64) / NJS;
    const int t = threadIdx.x, w = t >> 6, l = t & 63;
    const int gq = l >> 4, n16 = l & 15;
    const int wr = w % WR, js = w / WR;
    const int i0 = blockIdx.x * BM;
    const int cb = blockIdx.y;
    const int h = (hsel < 0) ? cb : hsel;
    const int ntg0 = cb * 4;
    const int arow = i0 + 16 * wr + n16;
    const float* srh = srv + (size_t)h * NN;
    const float sl_reg = slv[(size_t)h * NN + arow];

    __shared__ float accs[8][4][4][64];
    __shared__ float zp[NJS][BM];

    f32x4 acc[4];
    #pragma unroll
    for (int nt = 0; nt < 4; ++nt) acc[nt] = f32x4{0.f, 0.f, 0.f, 0.f};
    float zacc = 0.f;

#define LOADT(am_, bf_, tile_) do {                                              \
    const int tl_ = (tile_);                                                     \
    am_ = adjm[(size_t)arow * 32 + tl_];                                         \
    _Pragma("unroll")                                                            \
    for (int s_ = 0; s_ < 2; ++s_)                                               \
        _Pragma("unroll")                                                        \
        for (int nt_ = 0; nt_ < 4; ++nt_)                                        \
            bf_[s_][nt_] = *(const short8*)&gp[                                  \
                (size_t)((2 * tl_ + s_) * ntg_total + ntg0 + nt_) * 512 + l * 8];\
} while (0)

#define COMPT(am_, bf_, tile_) do {                                              \
    const int tl_ = (tile_);                                                     \
    f32x4 sr4_[4];                                                               \
    _Pragma("unroll")                                                            \
    for (int q_ = 0; q_ < 4; ++q_)                                               \
        sr4_[q_] = *(const f32x4*)&srh[64 * tl_ + 32 * (q_ >> 1) + 16 * (q_ & 1) + 4 * gq]; \
    short8 af_[2];                                                               \
    _Pragma("unroll")                                                            \
    for (int s_ = 0; s_ < 2; ++s_) {                                             \
        const unsigned am32_ = (unsigned)(am_ >> (32 * s_ + 4 * gq));            \
        _Pragma("unroll")                                                        \
        for (int hb_ = 0; hb_ < 2; ++hb_) {                                      \
            const f32x4 s4_ = sr4_[2 * s_ + hb_];                                \
            _Pragma("unroll")                                                    \
            for (int c_ = 0; c_ < 4; ++c_) {                                     \
                float f_ = sl_reg + s4_[c_];                                     \
                f_ = fmaxf(f_, 0.2f * f_);                                       \
                float wv_ = __builtin_amdgcn_exp2f(f_);                          \
                const int msk_ = (int)(am32_ << (31 - (c_ + 16 * hb_))) >> 31;   \
                wv_ = __int_as_float(__float_as_int(wv_) & msk_);                \
                zacc += wv_;                                                     \
                af_[s_][4 * hb_ + c_] = f2bfs(wv_);                              \
            }                                                                    \
        }                                                                        \
    }                                                                            \
    _Pragma("unroll")                                                            \
    for (int s_ = 0; s_ < 2; ++s_)                                               \
        _Pragma("unroll")                                                        \
        for (int nt_ = 0; nt_ < 4; ++nt_)                                        \
            acc[nt_] = __builtin_amdgcn_mfma_f32_16x16x32_bf16(                  \
                af_[s_], bf_[s_][nt_], acc[nt_], 0, 0, 0);                       \
} while (0)

    unsigned long long amA, amB;
    short8 bfA[2][4], bfB[2][4];

    LOADT(amA, bfA, js);
    LOADT(amB, bfB, js + NJS);

    for (int k = 0; k < NITER; k += 2) {
        COMPT(amA, bfA, js + k * NJS);
        {
            const int kn = (k + 2 < NITER) ? (k + 2) : (NITER - 1);
            LOADT(amA, bfA, js + kn * NJS);
        }
        COMPT(amB, bfB, js + (k + 1) * NJS);
        {
            const int kn = (k + 3 < NITER) ? (k + 3) : (NITER - 1);
            LOADT(amB, bfB, js + kn * NJS);
        }
    }
#undef LOADT
#undef COMPT

    zacc += __shfl_xor(zacc, 16);
    zacc += __shfl_xor(zacc, 32);
    if (l < 16) zp[js][16 * wr + l] = zacc;
    #pragma unroll
    for (int nt = 0; nt < 4; ++nt)
        #pragma unroll
        for (int r = 0; r < 4; ++r)
            accs[w][nt][r][l] = acc[nt][r];
    __syncthreads();

    #pragma unroll
    for (int idx = 0; idx < WR * 2; ++idx) {
        const int flat = w + 8 * idx;
        const int wr2 = flat >> 4, rem = flat & 15, nt = rem >> 2, r = rem & 3;
        const int ro = 16 * wr2 + 4 * gq + r;
        float z = 0.f, v = 0.f;
        #pragma unroll
        for (int jj = 0; jj < NJS; ++jj) {
            z += zp[jj][ro];
            v += accs[jj * WR + wr2][nt][r][l];
        }
        float o = v / z;
        if (do_elu) o = (o > 0.f) ? o : (__builtin_amdgcn_exp2f(o * LOG2E) - 1.f);
        out[(size_t)(i0 + ro) * out_cols + cb * 64 + nt * 16 + n16] = o;
    }
}

extern "C" void kernel_launch(void* const* d_in, const int* in_sizes, int n_in,
                              void* d_out, int out_size, void* d_ws, size_t ws_size,
                              hipStream_t stream)
{
    const float* x   = (const float*)d_in[0];   // 2048 x 512
    const int*   adj = (const int*)  d_in[1];   // 2048 x 2048
    const float* W1  = (const float*)d_in[2];   // 512 x 512
    const float* a1  = (const float*)d_in[3];   // 128
    const float* W2  = (const float*)d_in[4];   // 512 x 256
    const float* a2  = (const float*)d_in[5];   // 512
    float* out = (float*)d_out;                 // 2048 x 256

    float* g1  = (float*)d_ws;                  // 2048*512 fp32
    float* hb  = g1;                            // ALIAS: g1 dead once attn1 consumed it
    float* g2  = g1 + 2048 * 512;               // 2048*256 fp32
    float* sl1 = g2 + 2048 * 256;               // 8*2048 head-major
    float* sr1 = sl1 + 2048 * 8;
    float* sl2 = sr1 + 2048 * 8;
    float* sr2 = sl2 + 2048;
    unsigned long long* adjm = (unsigned long long*)(sr2 + 2048);   // 65536 u64
    unsigned short* gp  = (unsigned short*)(adjm + 65536);          // 2048 frags * 512
    unsigned short* axH = gp + 2048 * 512;      // x A-frags hi: 2048*512
    unsigned short* axL = axH + 2048 * 512;
    unsigned short* ahH = axL + 2048 * 512;     // hb A-frags hi
    unsigned short* ahL = ahH + 2048 * 512;
    unsigned short* w1H = ahL + 2048 * 512;     // W1 B-frags: 512*512
    unsigned short* w1L = w1H + 512 * 512;
    unsigned short* w2H = w1L + 512 * 512;      // W2 B-frags: 512*256
    unsigned short* w2L = w2H + 512 * 256;

    pack_adj<<<dim3(16384), 256, 0, stream>>>(adj, adjm);
    pack_b_split<<<dim3(128), 256, 0, stream>>>(W1, w1H, w1L, 512, 16);
    pack_b_split<<<dim3(64),  256, 0, stream>>>(W2, w2H, w2L, 256, 16);
    pack_a_split<<<dim3(512), 256, 0, stream>>>(x, axH, axL, 512);

    // ---- layer 1 ----
    gemm_mfma_split<<<dim3(32, 8), 256, 0, stream>>>(axH, axL, w1H, w1L, g1, 512, 16);
    score_fp32<<<dim3(4096), 256, 0, stream>>>(g1, a1, sl1, sr1, 512, 64, 8);
    pack_g<<<dim3(512), 256, 0, stream>>>(g1, gp, 512);
    attn_mfma4<32><<<dim3(64, 8), 512, 0, stream>>>(sl1, sr1, gp, adjm, hb, 512, -1, 1, 32);

    // ---- layer 2 ----
    pack_a_split<<<dim3(512), 256, 0, stream>>>(hb, ahH, ahL, 512);
    gemm_mfma_split<<<dim3(32, 4), 256, 0, stream>>>(ahH, ahL, w2H, w2L, g2, 256, 16);
    score_fp32<<<dim3(512), 256, 0, stream>>>(g2, a2, sl2, sr2, 256, 256, 1);
    pack_g<<<dim3(256), 256, 0, stream>>>(g2, gp, 256);
    attn_mfma4<16><<<dim3(128, 4), 512, 0, stream>>>(sl2, sr2, gp, adjm, out, 256, 0, 0, 16);
}

// Round 7
// 63.851 us; speedup vs baseline: 4.3997x; 1.2755x over previous
//
#include <hip/hip_runtime.h>
#include <hip/hip_bf16.h>
#include <math.h>

#define NN 2048
#define LOG2E 1.4426950408889634f

typedef __attribute__((ext_vector_type(8))) short short8;
typedef __attribute__((ext_vector_type(4))) short s16x4;
typedef __attribute__((ext_vector_type(4))) float f32x4;

__device__ inline unsigned short f2bfu(float f) {
    __hip_bfloat16 h = __float2bfloat16(f);
    return *reinterpret_cast<const unsigned short*>(&h);
}
__device__ inline short f2bfs(float f) {
    __hip_bfloat16 h = __float2bfloat16(f);
    return *reinterpret_cast<const short*>(&h);
}
__device__ inline float bfu2f(unsigned short u) {
    return __uint_as_float(((unsigned int)u) << 16);
}

// ---------------- adjacency -> per-row 64-bit masks; also zeroes score bufs -------
__global__ __launch_bounds__(256) void pack_adj(
    const int* __restrict__ adj, unsigned long long* __restrict__ adjm,
    float* __restrict__ zeros)   // 36864 floats: sl1,sr1,sl2,sr2 contiguous
{
    const int t = threadIdx.x, w = t >> 6, l = t & 63;
    if (blockIdx.x < 144) zeros[blockIdx.x * 256 + t] = 0.f;
    const int gw = blockIdx.x * 4 + w;
    const int row = gw >> 5, ch = gw & 31;
    const int v = adj[(size_t)row * NN + ch * 64 + l];
    const unsigned long long bm = __ballot(v != 0);
    if (l == 0) adjm[gw] = bm;
}

// ---------------- W1 + W2 (K x N fp32) -> split-bf16 B-frags (one kernel) ---------
// B-frag f = nt*KT + kt; lane l elem e: B[kt*32 + 4*(l>>4)+(e&3)+16*(e>>2)][nt*16+(l&15)]
__global__ __launch_bounds__(256) void pack_ws(
    const float* __restrict__ W1, unsigned short* __restrict__ w1H, unsigned short* __restrict__ w1L,
    const float* __restrict__ W2, unsigned short* __restrict__ w2H, unsigned short* __restrict__ w2L)
{
    const int t = threadIdx.x, w = t >> 6, l = t & 63;
    const int gq = l >> 4, n16 = l & 15;
    int f = blockIdx.x * 4 + w;          // 0..767
    const float* B; unsigned short *bH, *bL; int N;
    if (f < 512) { B = W1; bH = w1H; bL = w1L; N = 512; }
    else         { B = W2; bH = w2H; bL = w2L; N = 256; f -= 512; }
    const int KT = 16;
    const int nt = f / KT, kt = f - nt * KT;
    const int col = nt * 16 + n16;
    unsigned short uh[8], ul[8];
    #pragma unroll
    for (int e = 0; e < 8; ++e) {
        const int k = kt * 32 + 4 * gq + (e & 3) + 16 * (e >> 2);
        const float v = B[(size_t)k * N + col];
        const unsigned short h = f2bfu(v);
        uh[e] = h;
        ul[e] = f2bfu(v - bfu2f(h));
    }
    *(short8*)&bH[(size_t)f * 512 + l * 8] = *(const short8*)uh;
    *(short8*)&bL[(size_t)f * 512 + l * 8] = *(const short8*)ul;
}

// ---------------- A (M x K fp32) -> split-bf16 A-frags -----------------------------
__global__ __launch_bounds__(256) void pack_a_split(
    const float* __restrict__ A, unsigned short* __restrict__ aH,
    unsigned short* __restrict__ aL, int K)
{
    const int t = threadIdx.x, w = t >> 6, l = t & 63;
    const int gq = l >> 4, n16 = l & 15;
    const int KT = K >> 5;
    const int f = blockIdx.x * 4 + w;
    const int mt = f / KT, kt = f - mt * KT;
    const int row = mt * 16 + n16;
    const int k0 = kt * 32 + 4 * gq;
    unsigned short uh[8], ul[8];
    #pragma unroll
    for (int eh = 0; eh < 2; ++eh) {
        const float4 v4 = *(const float4*)&A[(size_t)row * K + k0 + 16 * eh];
        const float vv[4] = {v4.x, v4.y, v4.z, v4.w};
        #pragma unroll
        for (int c = 0; c < 4; ++c) {
            const float v = vv[c];
            const unsigned short h = f2bfu(v);
            uh[4 * eh + c] = h;
            ul[4 * eh + c] = f2bfu(v - bfu2f(h));
        }
    }
    *(short8*)&aH[(size_t)f * 512 + l * 8] = *(const short8*)uh;
    *(short8*)&aL[(size_t)f * 512 + l * 8] = *(const short8*)ul;
}

// ---------------- split-bf16 MFMA GEMM, fused epilogue -----------------------------
// C = A@B (AhBh+AhBl+AlBh). Epilogue (no C fp32 write):
//  (1) gpO: bf16 PV B-frags direct from acc (C-frag and B-frag share (gq,n16) map;
//      wave's 16-row tile fills elem-half mt&1 of frag jt=mt>>1).
//  (2) scores: sl/sr partial dots vs av segment, 16-lane reduce, atomicAdd (*LOG2E).
__global__ __launch_bounds__(256, 2) void gemm_fused(
    const unsigned short* __restrict__ aH, const unsigned short* __restrict__ aL,
    const unsigned short* __restrict__ bH, const unsigned short* __restrict__ bL,
    const float* __restrict__ av, unsigned short* __restrict__ gpO,
    float* __restrict__ slO, float* __restrict__ srO,
    int KT, int dh, int NT)
{
    const int t = threadIdx.x, w = t >> 6, l = t & 63;
    const int gq = l >> 4, n16 = l & 15;
    const int mt = blockIdx.x * 4 + w;
    const int cb = blockIdx.y;
    const int nt0 = cb * 4;
    const size_t abase = (size_t)mt * KT * 512 + l * 8;

    f32x4 acc[4];
    #pragma unroll
    for (int nt = 0; nt < 4; ++nt) acc[nt] = f32x4{0.f, 0.f, 0.f, 0.f};

#define GL(aH_v, aL_v, bH_v, bL_v, kt_) do {                                     \
    const int kk_ = (kt_);                                                       \
    aH_v = *(const short8*)&aH[abase + (size_t)kk_ * 512];                       \
    aL_v = *(const short8*)&aL[abase + (size_t)kk_ * 512];                       \
    _Pragma("unroll")                                                            \
    for (int nt_ = 0; nt_ < 4; ++nt_) {                                          \
        const size_t bo_ = ((size_t)(nt0 + nt_) * KT + kk_) * 512 + l * 8;       \
        bH_v[nt_] = *(const short8*)&bH[bo_];                                    \
        bL_v[nt_] = *(const short8*)&bL[bo_];                                    \
    }                                                                            \
} while (0)

#define GC(aH_v, aL_v, bH_v, bL_v) do {                                          \
    _Pragma("unroll")                                                            \
    for (int nt_ = 0; nt_ < 4; ++nt_) {                                          \
        acc[nt_] = __builtin_amdgcn_mfma_f32_16x16x32_bf16(aH_v, bH_v[nt_], acc[nt_], 0, 0, 0); \
        acc[nt_] = __builtin_amdgcn_mfma_f32_16x16x32_bf16(aH_v, bL_v[nt_], acc[nt_], 0, 0, 0); \
        acc[nt_] = __builtin_amdgcn_mfma_f32_16x16x32_bf16(aL_v, bH_v[nt_], acc[nt_], 0, 0, 0); \
    }                                                                            \
} while (0)

    short8 aHa, aLa, bHa[4], bLa[4], aHb, aLb, bHb[4], bLb[4];
    GL(aHa, aLa, bHa, bLa, 0);
    GL(aHb, aLb, bHb, bLb, 1);
    for (int kt = 0; kt < KT; kt += 2) {
        GC(aHa, aLa, bHa, bLa);
        if (kt + 2 < KT) GL(aHa, aLa, bHa, bLa, kt + 2);
        GC(aHb, aLb, bHb, bLb);
        if (kt + 3 < KT) GL(aHb, aLb, bHb, bLb, kt + 3);
    }
#undef GL
#undef GC

    // ---- (1) bf16 PV fragments ----
    #pragma unroll
    for (int nt = 0; nt < 4; ++nt) {
        s16x4 u;
        #pragma unroll
        for (int c = 0; c < 4; ++c) u[c] = (short)f2bfu(acc[nt][c]);
        const int f = (mt >> 1) * NT + (nt0 + nt);
        *(s16x4*)&gpO[(size_t)f * 512 + l * 8 + 4 * (mt & 1)] = u;
    }
    // ---- (2) scores ----
    const float* al = av;
    const float* ar = av + dh;
    float pl[4] = {0.f, 0.f, 0.f, 0.f}, pr[4] = {0.f, 0.f, 0.f, 0.f};
    #pragma unroll
    for (int nt = 0; nt < 4; ++nt) {
        const int q = (cb * 64 + 16 * nt + n16) & (dh - 1);
        const float wl = al[q], wr_ = ar[q];
        #pragma unroll
        for (int r = 0; r < 4; ++r) { pl[r] += acc[nt][r] * wl; pr[r] += acc[nt][r] * wr_; }
    }
    #pragma unroll
    for (int r = 0; r < 4; ++r) {
        #pragma unroll
        for (int off = 1; off < 16; off <<= 1) {
            pl[r] += __shfl_xor(pl[r], off);
            pr[r] += __shfl_xor(pr[r], off);
        }
    }
    if (n16 == 0) {
        const int hbase = (dh == 64 ? cb : 0) * NN;
        #pragma unroll
        for (int r = 0; r < 4; ++r) {
            const int grow = 16 * mt + 4 * gq + r;
            atomicAdd(&slO[hbase + grow], pl[r] * LOG2E);
            atomicAdd(&srO[hbase + grow], pr[r] * LOG2E);
        }
    }
}

// ---------------- fused masked-softmax attention, register ping-pong MFMA ---------
// OUTMODE 0: fp32 out. OUTMODE 1 (BM=32 only): emit split-bf16 A-frags for next GEMM
// (transpose via the accs LDS tile; ELU applied; hi/lo planes).
template<int BM, int OUTMODE>
__global__ __launch_bounds__(512, 4) void attn_mfma5(
    const float* __restrict__ slv, const float* __restrict__ srv,
    const unsigned short* __restrict__ gp, const unsigned long long* __restrict__ adjm,
    float* __restrict__ out, unsigned short* __restrict__ aoH, unsigned short* __restrict__ aoL,
    int out_cols, int hsel, int do_elu, int ntg_total)
{
    constexpr int WR = BM / 16;
    constexpr int NJS = 8 / WR;
    constexpr int NITER = (NN / 64) / NJS;
    const int t = threadIdx.x, w = t >> 6, l = t & 63;
    const int gq = l >> 4, n16 = l & 15;
    const int wr = w % WR, js = w / WR;
    const int i0 = blockIdx.x * BM;
    const int cb = blockIdx.y;
    const int h = (hsel < 0) ? cb : hsel;
    const int ntg0 = cb * 4;
    const int arow = i0 + 16 * wr + n16;
    const float* srh = srv + (size_t)h * NN;
    const float sl_reg = slv[(size_t)h * NN + arow];

    __shared__ float accs[8][4][4][65];   // padded: conflict-free transposed read
    __shared__ float zp[NJS][BM];

    f32x4 acc[4];
    #pragma unroll
    for (int nt = 0; nt < 4; ++nt) acc[nt] = f32x4{0.f, 0.f, 0.f, 0.f};
    float zacc = 0.f;

#define LOADT(am_, bf_, tile_) do {                                              \
    const int tl_ = (tile_);                                                     \
    am_ = adjm[(size_t)arow * 32 + tl_];                                         \
    _Pragma("unroll")                                                            \
    for (int s_ = 0; s_ < 2; ++s_)                                               \
        _Pragma("unroll")                                                        \
        for (int nt_ = 0; nt_ < 4; ++nt_)                                        \
            bf_[s_][nt_] = *(const short8*)&gp[                                  \
                (size_t)((2 * tl_ + s_) * ntg_total + ntg0 + nt_) * 512 + l * 8];\
} while (0)

#define COMPT(am_, bf_, tile_) do {                                              \
    const int tl_ = (tile_);                                                     \
    f32x4 sr4_[4];                                                               \
    _Pragma("unroll")                                                            \
    for (int q_ = 0; q_ < 4; ++q_)                                               \
        sr4_[q_] = *(const f32x4*)&srh[64 * tl_ + 32 * (q_ >> 1) + 16 * (q_ & 1) + 4 * gq]; \
    short8 af_[2];                                                               \
    _Pragma("unroll")                                                            \
    for (int s_ = 0; s_ < 2; ++s_) {                                             \
        const unsigned am32_ = (unsigned)(am_ >> (32 * s_ + 4 * gq));            \
        _Pragma("unroll")                                                        \
        for (int hb_ = 0; hb_ < 2; ++hb_) {                                      \
            const f32x4 s4_ = sr4_[2 * s_ + hb_];                                \
            _Pragma("unroll")                                                    \
            for (int c_ = 0; c_ < 4; ++c_) {                                     \
                float f_ = sl_reg + s4_[c_];                                     \
                f_ = fmaxf(f_, 0.2f * f_);                                       \
                float wv_ = __builtin_amdgcn_exp2f(f_);                          \
                const int msk_ = (int)(am32_ << (31 - (c_ + 16 * hb_))) >> 31;   \
                wv_ = __int_as_float(__float_as_int(wv_) & msk_);                \
                zacc += wv_;                                                     \
                af_[s_][4 * hb_ + c_] = f2bfs(wv_);                              \
            }                                                                    \
        }                                                                        \
    }                                                                            \
    _Pragma("unroll")                                                            \
    for (int s_ = 0; s_ < 2; ++s_)                                               \
        _Pragma("unroll")                                                        \
        for (int nt_ = 0; nt_ < 4; ++nt_)                                        \
            acc[nt_] = __builtin_amdgcn_mfma_f32_16x16x32_bf16(                  \
                af_[s_], bf_[s_][nt_], acc[nt_], 0, 0, 0);                       \
} while (0)

    unsigned long long amA, amB;
    short8 bfA[2][4], bfB[2][4];

    LOADT(amA, bfA, js);
    LOADT(amB, bfB, js + NJS);

    for (int k = 0; k < NITER; k += 2) {
        COMPT(amA, bfA, js + k * NJS);
        {
            const int kn = (k + 2 < NITER) ? (k + 2) : (NITER - 1);
            LOADT(amA, bfA, js + kn * NJS);
        }
        COMPT(amB, bfB, js + (k + 1) * NJS);
        {
            const int kn = (k + 3 < NITER) ? (k + 3) : (NITER - 1);
            LOADT(amB, bfB, js + kn * NJS);
        }
    }
#undef LOADT
#undef COMPT

    zacc += __shfl_xor(zacc, 16);
    zacc += __shfl_xor(zacc, 32);
    if (l < 16) zp[js][16 * wr + l] = zacc;
    #pragma unroll
    for (int nt = 0; nt < 4; ++nt)
        #pragma unroll
        for (int r = 0; r < 4; ++r)
            accs[w][nt][r][l] = acc[nt][r];
    __syncthreads();

    if constexpr (OUTMODE == 0) {
        #pragma unroll
        for (int idx = 0; idx < WR * 2; ++idx) {
            const int flat = w + 8 * idx;
            const int wr2 = flat >> 4, rem = flat & 15, nt = rem >> 2, r = rem & 3;
            const int ro = 16 * wr2 + 4 * gq + r;
            float z = 0.f, v = 0.f;
            #pragma unroll
            for (int jj = 0; jj < NJS; ++jj) {
                z += zp[jj][ro];
                v += accs[jj * WR + wr2][nt][r][l];
            }
            float o = v / z;
            if (do_elu) o = (o > 0.f) ? o : (__builtin_amdgcn_exp2f(o * LOG2E) - 1.f);
            out[(size_t)(i0 + ro) * out_cols + cb * 64 + nt * 16 + n16] = o;
        }
    } else {
        // wave w -> frag (mtl = (w>>1)&1, ktl = w&1), elem-half eh = w>>2.
        const int mtl = (w >> 1) & 1, ktl = w & 1, eh = w >> 2;
        const int rowl = l & 15, colq = l >> 4;
        const int grow = 16 * mtl + rowl;              // row within 32-row tile
        float z = 0.f;
        #pragma unroll
        for (int jj = 0; jj < NJS; ++jj) z += zp[jj][grow];
        const float rz = 1.0f / z;
        const int wr2 = mtl, srcr = rowl & 3, srcgq = (rowl >> 2) & 3;
        unsigned short uh[4], ul[4];
        #pragma unroll
        for (int c = 0; c < 4; ++c) {
            const int col = 32 * ktl + 16 * eh + 4 * colq + c;   // within 64-col tile
            const int nt = col >> 4, c16 = col & 15;
            float v = 0.f;
            #pragma unroll
            for (int jj = 0; jj < NJS; ++jj)
                v += accs[jj * WR + wr2][nt][srcr][srcgq * 16 + c16];
            float o = v * rz;
            o = (o > 0.f) ? o : (__builtin_amdgcn_exp2f(o * LOG2E) - 1.f);   // ELU
            const unsigned short hi = f2bfu(o);
            uh[c] = hi;
            ul[c] = f2bfu(o - bfu2f(hi));
        }
        const int mt = (i0 >> 4) + mtl, kt = 2 * cb + ktl;       // KT = 16
        const size_t off = ((size_t)mt * 16 + kt) * 512 + l * 8 + 4 * eh;
        *(s16x4*)&aoH[off] = *(const s16x4*)uh;
        *(s16x4*)&aoL[off] = *(const s16x4*)ul;
    }
}

extern "C" void kernel_launch(void* const* d_in, const int* in_sizes, int n_in,
                              void* d_out, int out_size, void* d_ws, size_t ws_size,
                              hipStream_t stream)
{
    const float* x   = (const float*)d_in[0];   // 2048 x 512
    const int*   adj = (const int*)  d_in[1];   // 2048 x 2048
    const float* W1  = (const float*)d_in[2];   // 512 x 512
    const float* a1  = (const float*)d_in[3];   // 128
    const float* W2  = (const float*)d_in[4];   // 512 x 256
    const float* a2  = (const float*)d_in[5];   // 512
    float* out = (float*)d_out;                 // 2048 x 256

    // ---- workspace layout (scores first: zeroed by pack_adj, 36864 floats) ----
    float* sl1 = (float*)d_ws;                  // 8*2048
    float* sr1 = sl1 + 8 * 2048;
    float* sl2 = sr1 + 8 * 2048;                // 2048
    float* sr2 = sl2 + 2048;
    unsigned long long* adjm = (unsigned long long*)(sr2 + 2048);   // 65536 u64
    unsigned short* gp1 = (unsigned short*)(adjm + 65536);          // 2048 frags * 512
    unsigned short* gp2 = gp1 + 2048 * 512;     // 1024 frags
    unsigned short* axH = gp2 + 1024 * 512;     // x A-frags: 2048 frags
    unsigned short* axL = axH + 2048 * 512;
    unsigned short* ahH = axL + 2048 * 512;     // hb A-frags: 2048 frags
    unsigned short* ahL = ahH + 2048 * 512;
    unsigned short* w1H = ahL + 2048 * 512;     // W1 B-frags: 512 frags
    unsigned short* w1L = w1H + 512 * 512;
    unsigned short* w2H = w1L + 512 * 512;      // W2 B-frags: 256 frags
    unsigned short* w2L = w2H + 256 * 512;

    pack_adj<<<dim3(16384), 256, 0, stream>>>(adj, adjm, sl1);
    pack_ws<<<dim3(192), 256, 0, stream>>>(W1, w1H, w1L, W2, w2H, w2L);
    pack_a_split<<<dim3(512), 256, 0, stream>>>(x, axH, axL, 512);

    // ---- layer 1: GEMM(+gp1+scores) -> attn(+A-frags for layer 2) ----
    gemm_fused<<<dim3(32, 8), 256, 0, stream>>>(axH, axL, w1H, w1L, a1, gp1, sl1, sr1, 16, 64, 32);
    attn_mfma5<32, 1><<<dim3(64, 8), 512, 0, stream>>>(sl1, sr1, gp1, adjm,
                                                       nullptr, ahH, ahL, 512, -1, 1, 32);

    // ---- layer 2: GEMM(+gp2+scores) -> attn -> out ----
    gemm_fused<<<dim3(32, 4), 256, 0, stream>>>(ahH, ahL, w2H, w2L, a2, gp2, sl2, sr2, 16, 256, 16);
    attn_mfma5<16, 0><<<dim3(128, 4), 512, 0, stream>>>(sl2, sr2, gp2, adjm,
                                                        out, nullptr, nullptr, 256, 0, 0, 16);
}

// Round 8
// 56.212 us; speedup vs baseline: 4.9977x; 1.1359x over previous
//
#include <hip/hip_runtime.h>
#include <hip/hip_bf16.h>
#include <math.h>

#define NN 2048
#define LOG2E 1.4426950408889634f

typedef __attribute__((ext_vector_type(8))) short short8;
typedef __attribute__((ext_vector_type(4))) short s16x4;
typedef __attribute__((ext_vector_type(4))) float f32x4;

__device__ inline unsigned short f2bfu(float f) {
    __hip_bfloat16 h = __float2bfloat16(f);
    return *reinterpret_cast<const unsigned short*>(&h);
}
__device__ inline short f2bfs(float f) {
    __hip_bfloat16 h = __float2bfloat16(f);
    return *reinterpret_cast<const short*>(&h);
}
__device__ inline float bfu2f(unsigned short u) {
    return __uint_as_float(((unsigned int)u) << 16);
}

// ---------------- fused prep: adj masks + score-zero + W packs + x A-frags --------
__global__ __launch_bounds__(256) void prep(
    const int* __restrict__ adj, unsigned long long* __restrict__ adjm,
    float* __restrict__ zeros,
    const float* __restrict__ W1, unsigned short* __restrict__ w1H, unsigned short* __restrict__ w1L,
    const float* __restrict__ W2, unsigned short* __restrict__ w2H, unsigned short* __restrict__ w2L,
    const float* __restrict__ x, unsigned short* __restrict__ axH, unsigned short* __restrict__ axL)
{
    const int b = blockIdx.x, t = threadIdx.x, w = t >> 6, l = t & 63;
    const int gq = l >> 4, n16 = l & 15;
    // --- adjacency -> per-row 64-bit masks (all 16384 blocks) ---
    {
        const int gw = b * 4 + w;
        const int row = gw >> 5, ch = gw & 31;
        const int v = adj[(size_t)row * NN + ch * 64 + l];
        const unsigned long long bm = __ballot(v != 0);
        if (l == 0) adjm[gw] = bm;
    }
    if (b < 144) {
        zeros[b * 256 + t] = 0.f;           // sl1,sr1,sl2,sr2 (36864 floats)
    } else if (b >= 256 && b < 448) {
        // --- W1/W2 -> split-bf16 B-frags ---
        int f = (b - 256) * 4 + w;          // 0..767
        const float* B; unsigned short *bH, *bL; int N;
        if (f < 512) { B = W1; bH = w1H; bL = w1L; N = 512; }
        else         { B = W2; bH = w2H; bL = w2L; N = 256; f -= 512; }
        const int nt = f >> 4, kt = f & 15;
        const int col = nt * 16 + n16;
        unsigned short uh[8], ul[8];
        #pragma unroll
        for (int e = 0; e < 8; ++e) {
            const int k = kt * 32 + 4 * gq + (e & 3) + 16 * (e >> 2);
            const float v = B[(size_t)k * N + col];
            const unsigned short hi = f2bfu(v);
            uh[e] = hi;
            ul[e] = f2bfu(v - bfu2f(hi));
        }
        *(short8*)&bH[(size_t)f * 512 + l * 8] = *(const short8*)uh;
        *(short8*)&bL[(size_t)f * 512 + l * 8] = *(const short8*)ul;
    } else if (b >= 448 && b < 960) {
        // --- x -> split-bf16 A-frags (K=512, KT=16) ---
        const int f = (b - 448) * 4 + w;    // 0..2047
        const int mt = f >> 4, kt = f & 15;
        const int row = mt * 16 + n16;
        const int k0 = kt * 32 + 4 * gq;
        unsigned short uh[8], ul[8];
        #pragma unroll
        for (int eh = 0; eh < 2; ++eh) {
            const float4 v4 = *(const float4*)&x[(size_t)row * 512 + k0 + 16 * eh];
            const float vv[4] = {v4.x, v4.y, v4.z, v4.w};
            #pragma unroll
            for (int c = 0; c < 4; ++c) {
                const float v = vv[c];
                const unsigned short hi = f2bfu(v);
                uh[4 * eh + c] = hi;
                ul[4 * eh + c] = f2bfu(v - bfu2f(hi));
            }
        }
        *(short8*)&axH[(size_t)f * 512 + l * 8] = *(const short8*)uh;
        *(short8*)&axL[(size_t)f * 512 + l * 8] = *(const short8*)ul;
    }
}

// ---------------- split-bf16 MFMA GEMM, fused epilogue (unchanged from R7) ---------
__global__ __launch_bounds__(256, 2) void gemm_fused(
    const unsigned short* __restrict__ aH, const unsigned short* __restrict__ aL,
    const unsigned short* __restrict__ bH, const unsigned short* __restrict__ bL,
    const float* __restrict__ av, unsigned short* __restrict__ gpO,
    float* __restrict__ slO, float* __restrict__ srO,
    int KT, int dh, int NT)
{
    const int t = threadIdx.x, w = t >> 6, l = t & 63;
    const int gq = l >> 4, n16 = l & 15;
    const int mt = blockIdx.x * 4 + w;
    const int cb = blockIdx.y;
    const int nt0 = cb * 4;
    const size_t abase = (size_t)mt * KT * 512 + l * 8;

    f32x4 acc[4];
    #pragma unroll
    for (int nt = 0; nt < 4; ++nt) acc[nt] = f32x4{0.f, 0.f, 0.f, 0.f};

#define GL(aH_v, aL_v, bH_v, bL_v, kt_) do {                                     \
    const int kk_ = (kt_);                                                       \
    aH_v = *(const short8*)&aH[abase + (size_t)kk_ * 512];                       \
    aL_v = *(const short8*)&aL[abase + (size_t)kk_ * 512];                       \
    _Pragma("unroll")                                                            \
    for (int nt_ = 0; nt_ < 4; ++nt_) {                                          \
        const size_t bo_ = ((size_t)(nt0 + nt_) * KT + kk_) * 512 + l * 8;       \
        bH_v[nt_] = *(const short8*)&bH[bo_];                                    \
        bL_v[nt_] = *(const short8*)&bL[bo_];                                    \
    }                                                                            \
} while (0)

#define GC(aH_v, aL_v, bH_v, bL_v) do {                                          \
    _Pragma("unroll")                                                            \
    for (int nt_ = 0; nt_ < 4; ++nt_) {                                          \
        acc[nt_] = __builtin_amdgcn_mfma_f32_16x16x32_bf16(aH_v, bH_v[nt_], acc[nt_], 0, 0, 0); \
        acc[nt_] = __builtin_amdgcn_mfma_f32_16x16x32_bf16(aH_v, bL_v[nt_], acc[nt_], 0, 0, 0); \
        acc[nt_] = __builtin_amdgcn_mfma_f32_16x16x32_bf16(aL_v, bH_v[nt_], acc[nt_], 0, 0, 0); \
    }                                                                            \
} while (0)

    short8 aHa, aLa, bHa[4], bLa[4], aHb, aLb, bHb[4], bLb[4];
    GL(aHa, aLa, bHa, bLa, 0);
    GL(aHb, aLb, bHb, bLb, 1);
    for (int kt = 0; kt < KT; kt += 2) {
        GC(aHa, aLa, bHa, bLa);
        if (kt + 2 < KT) GL(aHa, aLa, bHa, bLa, kt + 2);
        GC(aHb, aLb, bHb, bLb);
        if (kt + 3 < KT) GL(aHb, aLb, bHb, bLb, kt + 3);
    }
#undef GL
#undef GC

    // (1) bf16 PV fragments direct from acc
    #pragma unroll
    for (int nt = 0; nt < 4; ++nt) {
        s16x4 u;
        #pragma unroll
        for (int c = 0; c < 4; ++c) u[c] = (short)f2bfu(acc[nt][c]);
        const int f = (mt >> 1) * NT + (nt0 + nt);
        *(s16x4*)&gpO[(size_t)f * 512 + l * 8 + 4 * (mt & 1)] = u;
    }
    // (2) scores via 16-lane reduce + atomicAdd
    const float* al = av;
    const float* ar = av + dh;
    float pl[4] = {0.f, 0.f, 0.f, 0.f}, pr[4] = {0.f, 0.f, 0.f, 0.f};
    #pragma unroll
    for (int nt = 0; nt < 4; ++nt) {
        const int q = (cb * 64 + 16 * nt + n16) & (dh - 1);
        const float wl = al[q], wr_ = ar[q];
        #pragma unroll
        for (int r = 0; r < 4; ++r) { pl[r] += acc[nt][r] * wl; pr[r] += acc[nt][r] * wr_; }
    }
    #pragma unroll
    for (int r = 0; r < 4; ++r) {
        #pragma unroll
        for (int off = 1; off < 16; off <<= 1) {
            pl[r] += __shfl_xor(pl[r], off);
            pr[r] += __shfl_xor(pr[r], off);
        }
    }
    if (n16 == 0) {
        const int hbase = (dh == 64 ? cb : 0) * NN;
        #pragma unroll
        for (int r = 0; r < 4; ++r) {
            const int grow = 16 * mt + 4 * gq + r;
            atomicAdd(&slO[hbase + grow], pl[r] * LOG2E);
            atomicAdd(&srO[hbase + grow], pr[r] * LOG2E);
        }
    }
}

// ---------------- fused masked-softmax attention, MT row-tiles/wave ----------------
// All 8 waves cover the same MT*16 rows; js = w (8-way j-split), NITER = 4 tiles.
// Half-tile ping-pong: buffer = {4 B-frags, 2 sr-vec4, MT u32 masks} per 32-j half.
// B-traffic amortized over MT*16 rows per read.
template<int MT, int OUTMODE>
__global__ __launch_bounds__(512, 4) void attn_mfma6(
    const float* __restrict__ slv, const float* __restrict__ srv,
    const unsigned short* __restrict__ gp, const unsigned int* __restrict__ adjm32,
    float* __restrict__ out, unsigned short* __restrict__ aoH, unsigned short* __restrict__ aoL,
    int out_cols, int hsel, int do_elu, int ntg_total)
{
    const int t = threadIdx.x, w = t >> 6, l = t & 63;
    const int gq = l >> 4, n16 = l & 15;
    const int i0 = blockIdx.x * (MT * 16);
    const int cb = blockIdx.y;
    const int h = (hsel < 0) ? cb : hsel;
    const int ntg0 = cb * 4;
    const float* srh = srv + (size_t)h * NN;
    int arow[MT];
    float slr[MT];
    #pragma unroll
    for (int mt = 0; mt < MT; ++mt) {
        arow[mt] = i0 + 16 * mt + n16;
        slr[mt] = slv[(size_t)h * NN + arow[mt]];
    }

    __shared__ float accs_raw[8320];   // 33280 B, 65-padded rows
    __shared__ float zp[8][MT * 16];

    f32x4 acc[MT][4];
    float zacc[MT];
    #pragma unroll
    for (int mt = 0; mt < MT; ++mt) {
        zacc[mt] = 0.f;
        #pragma unroll
        for (int nt = 0; nt < 4; ++nt) acc[mt][nt] = f32x4{0.f, 0.f, 0.f, 0.f};
    }

#define LOADH(bf_, sr_, am_, tile_, s_) do {                                     \
    const int tl_ = (tile_);                                                     \
    _Pragma("unroll")                                                            \
    for (int nt_ = 0; nt_ < 4; ++nt_)                                            \
        bf_[nt_] = *(const short8*)&gp[                                          \
            (size_t)((2 * tl_ + (s_)) * ntg_total + ntg0 + nt_) * 512 + l * 8];  \
    _Pragma("unroll")                                                            \
    for (int hb_ = 0; hb_ < 2; ++hb_)                                            \
        sr_[hb_] = *(const f32x4*)&srh[64 * tl_ + 32 * (s_) + 16 * hb_ + 4 * gq];\
    _Pragma("unroll")                                                            \
    for (int mt_ = 0; mt_ < MT; ++mt_)                                           \
        am_[mt_] = adjm32[((size_t)arow[mt_] * 32 + tl_) * 2 + (s_)];            \
} while (0)

#define COMPH(bf_, sr_, am_) do {                                                \
    short8 af_[MT];                                                              \
    _Pragma("unroll")                                                            \
    for (int mt_ = 0; mt_ < MT; ++mt_) {                                         \
        const unsigned am32_ = am_[mt_] >> (4 * gq);                             \
        _Pragma("unroll")                                                        \
        for (int hb_ = 0; hb_ < 2; ++hb_) {                                      \
            const f32x4 s4_ = sr_[hb_];                                          \
            _Pragma("unroll")                                                    \
            for (int c_ = 0; c_ < 4; ++c_) {                                     \
                float f_ = slr[mt_] + s4_[c_];                                   \
                f_ = fmaxf(f_, 0.2f * f_);                                       \
                float wv_ = __builtin_amdgcn_exp2f(f_);                          \
                const int msk_ = (int)(am32_ << (31 - (c_ + 16 * hb_))) >> 31;   \
                wv_ = __int_as_float(__float_as_int(wv_) & msk_);                \
                zacc[mt_] += wv_;                                                \
                af_[mt_][4 * hb_ + c_] = f2bfs(wv_);                             \
            }                                                                    \
        }                                                                        \
    }                                                                            \
    _Pragma("unroll")                                                            \
    for (int mt_ = 0; mt_ < MT; ++mt_)                                           \
        _Pragma("unroll")                                                        \
        for (int nt_ = 0; nt_ < 4; ++nt_)                                        \
            acc[mt_][nt_] = __builtin_amdgcn_mfma_f32_16x16x32_bf16(             \
                af_[mt_], bf_[nt_], acc[mt_][nt_], 0, 0, 0);                     \
} while (0)

    unsigned amA[MT], amB[MT];
    f32x4 srA[2], srB[2];
    short8 bfA[4], bfB[4];

    LOADH(bfA, srA, amA, w, 0);
    LOADH(bfB, srB, amB, w, 1);
    #pragma unroll
    for (int k = 0; k < 4; ++k) {
        const int tn = (k < 3) ? (w + 8 * (k + 1)) : (w + 8 * k);   // guarded prefetch
        COMPH(bfA, srA, amA);
        LOADH(bfA, srA, amA, tn, 0);
        COMPH(bfB, srB, amB);
        LOADH(bfB, srB, amB, tn, 1);
    }
#undef LOADH
#undef COMPH

    // ---- Z reduce: lanes {l, l^16, l^32, l^48} share a row ----
    #pragma unroll
    for (int mt = 0; mt < MT; ++mt) {
        zacc[mt] += __shfl_xor(zacc[mt], 16);
        zacc[mt] += __shfl_xor(zacc[mt], 32);
    }
    if (l < 16) {
        #pragma unroll
        for (int mt = 0; mt < MT; ++mt) zp[w][16 * mt + l] = zacc[mt];
    }

    if constexpr (OUTMODE == 0) {
        // MT == 1: single round, fp32 out
        #pragma unroll
        for (int nt = 0; nt < 4; ++nt)
            #pragma unroll
            for (int r = 0; r < 4; ++r)
                accs_raw[((w * 4 + nt) * 4 + r) * 65 + l] = acc[0][nt][r];
        __syncthreads();
        #pragma unroll
        for (int idx = 0; idx < 2; ++idx) {
            const int flat = w + 8 * idx;            // 0..15
            const int nt = flat >> 2, r = flat & 3;
            const int ro = 4 * gq + r;
            float z = 0.f, v = 0.f;
            #pragma unroll
            for (int jj = 0; jj < 8; ++jj) {
                z += zp[jj][ro];
                v += accs_raw[((jj * 4 + nt) * 4 + r) * 65 + l];
            }
            float o = v / z;
            if (do_elu) o = (o > 0.f) ? o : (__builtin_amdgcn_exp2f(o * LOG2E) - 1.f);
            out[(size_t)(i0 + ro) * out_cols + cb * 64 + nt * 16 + n16] = o;
        }
    } else {
        // MT == 2: two rounds (one per ktl); emit split-bf16 A-frags (ELU applied)
        const int mtl = w & 1, eh = (w >> 1) & 1;
        const int rowl = l & 15, colq = l >> 4;
        #pragma unroll
        for (int h2 = 0; h2 < 2; ++h2) {
            #pragma unroll
            for (int mt = 0; mt < MT; ++mt)
                #pragma unroll
                for (int ntl = 0; ntl < 2; ++ntl)
                    #pragma unroll
                    for (int r = 0; r < 4; ++r)
                        accs_raw[(((w * 2 + mt) * 2 + ntl) * 4 + r) * 65 + l] =
                            acc[mt][2 * h2 + ntl][r];
            __syncthreads();
            if (w < 4) {
                const int grow = 16 * mtl + rowl;
                float z = 0.f;
                #pragma unroll
                for (int jj = 0; jj < 8; ++jj) z += zp[jj][grow];
                const float rz = 1.0f / z;
                unsigned short uh[4], ul[4];
                #pragma unroll
                for (int c = 0; c < 4; ++c) {
                    const int c16 = 4 * colq + c;
                    float v = 0.f;
                    #pragma unroll
                    for (int jj = 0; jj < 8; ++jj)
                        v += accs_raw[(((jj * 2 + mtl) * 2 + eh) * 4 + (rowl & 3)) * 65
                                      + (rowl >> 2) * 16 + c16];
                    float o = v * rz;
                    o = (o > 0.f) ? o : (__builtin_amdgcn_exp2f(o * LOG2E) - 1.f);  // ELU
                    const unsigned short hi = f2bfu(o);
                    uh[c] = hi;
                    ul[c] = f2bfu(o - bfu2f(hi));
                }
                const int mtg = blockIdx.x * 2 + mtl;
                const int kt = 2 * cb + h2;
                const size_t off = ((size_t)mtg * 16 + kt) * 512 + l * 8 + 4 * eh;
                *(s16x4*)&aoH[off] = *(const s16x4*)uh;
                *(s16x4*)&aoL[off] = *(const s16x4*)ul;
            }
            __syncthreads();
        }
    }
}

extern "C" void kernel_launch(void* const* d_in, const int* in_sizes, int n_in,
                              void* d_out, int out_size, void* d_ws, size_t ws_size,
                              hipStream_t stream)
{
    const float* x   = (const float*)d_in[0];   // 2048 x 512
    const int*   adj = (const int*)  d_in[1];   // 2048 x 2048
    const float* W1  = (const float*)d_in[2];   // 512 x 512
    const float* a1  = (const float*)d_in[3];   // 128
    const float* W2  = (const float*)d_in[4];   // 512 x 256
    const float* a2  = (const float*)d_in[5];   // 512
    float* out = (float*)d_out;                 // 2048 x 256

    // ---- workspace layout (scores first: zeroed by prep, 36864 floats) ----
    float* sl1 = (float*)d_ws;                  // 8*2048
    float* sr1 = sl1 + 8 * 2048;
    float* sl2 = sr1 + 8 * 2048;                // 2048
    float* sr2 = sl2 + 2048;
    unsigned long long* adjm = (unsigned long long*)(sr2 + 2048);   // 65536 u64
    unsigned short* gp1 = (unsigned short*)(adjm + 65536);          // 2048 frags * 512
    unsigned short* gp2 = gp1 + 2048 * 512;     // 1024 frags
    unsigned short* axH = gp2 + 1024 * 512;     // x A-frags: 2048 frags
    unsigned short* axL = axH + 2048 * 512;
    unsigned short* ahH = axL + 2048 * 512;     // hb A-frags: 2048 frags
    unsigned short* ahL = ahH + 2048 * 512;
    unsigned short* w1H = ahL + 2048 * 512;     // W1 B-frags: 512 frags
    unsigned short* w1L = w1H + 512 * 512;
    unsigned short* w2H = w1L + 512 * 512;      // W2 B-frags: 256 frags
    unsigned short* w2L = w2H + 256 * 512;

    prep<<<dim3(16384), 256, 0, stream>>>(adj, adjm, sl1,
                                          W1, w1H, w1L, W2, w2H, w2L, x, axH, axL);

    // ---- layer 1 ----
    gemm_fused<<<dim3(32, 8), 256, 0, stream>>>(axH, axL, w1H, w1L, a1, gp1, sl1, sr1, 16, 64, 32);
    attn_mfma6<2, 1><<<dim3(64, 8), 512, 0, stream>>>(sl1, sr1, gp1, (const unsigned int*)adjm,
                                                      nullptr, ahH, ahL, 512, -1, 1, 32);

    // ---- layer 2 ----
    gemm_fused<<<dim3(32, 4), 256, 0, stream>>>(ahH, ahL, w2H, w2L, a2, gp2, sl2, sr2, 16, 256, 16);
    attn_mfma6<1, 0><<<dim3(128, 4), 512, 0, stream>>>(sl2, sr2, gp2, (const unsigned int*)adjm,
                                                       out, nullptr, nullptr, 256, 0, 0, 16);
}